// Round 7
// baseline (139.086 us; speedup 1.0000x reference)
//
#include <hip/hip_runtime.h>
#include <math.h>

// Deepmd angular descriptor, f32 in / f32 out. B=8, N=4096, M=96, OUT_W=384.
//
// R7 vs R6 (49.9 us, VALU 20%, HBM 21% -> latency-bound): split into
//   (1) pure zero-fill kernel for the 49 MB output (fillBufferAligned-class
//       store stream, measured 6.2 TB/s on this chip => ~8 us), then
//   (2) store-free compute kernel (R5's best-measured 192-thread shape):
//       reads the 63 MB input stream, computes cut, and only the ~0.45%
//       nonzero lanes rank + scatter 12 B to global. No out_s LDS row, no
//       second barrier, no full-row emit. Stream order fills before scatter.
#define M_NB  96
#define OUT_W 384
#define PPB   2            // pairs per compute block; 2*96 = 192 threads

__global__ __launch_bounds__(256) void fill_zero_kernel(float4* __restrict__ out4,
                                                        int total4)
{
    const int stride = gridDim.x * 256;
    const float4 z4 = make_float4(0.f, 0.f, 0.f, 0.f);
    #pragma unroll 4
    for (int i = blockIdx.x * 256 + threadIdx.x; i < total4; i += stride)
        out4[i] = z4;
}

__global__ __launch_bounds__(PPB * M_NB) void deepmd_angular_compute(
    const float* __restrict__ positions,  // [B,N,3]
    const float* __restrict__ cell,       // [B,3,3]
    const float* __restrict__ offsets,    // [B,N,M,3]
    const float* __restrict__ mask,       // [B,N,M]
    const int*   __restrict__ neighbors,  // [B,N,M]
    float*       __restrict__ out,        // [B,N,OUT_W], pre-zeroed
    int N)
{
    __shared__ float cut_s[PPB][M_NB];

    const int m  = threadIdx.x;              // 0..95  neighbor index
    const int pr = threadIdx.y;              // 0..PPB-1
    const int p  = blockIdx.x * PPB + pr;    // global (b,n) pair index
    const int b  = p / N;

    // ---- per-neighbor inputs (all independent streaming loads) ----
    const long base_nm = (long)p * M_NB + m;
    const int   j   = neighbors[base_nm];
    const float msk = mask[base_nm];
    const float o0  = offsets[base_nm * 3 + 0];
    const float o1  = offsets[base_nm * 3 + 1];
    const float o2  = offsets[base_nm * 3 + 2];

    const float* cb = cell + (long)b * 9;    // row-major [3][3]
    const float c00 = cb[0], c01 = cb[1], c02 = cb[2];
    const float c10 = cb[3], c11 = cb[4], c12 = cb[5];
    const float c20 = cb[6], c21 = cb[7], c22 = cb[8];

    const float* pi_ = positions + (long)p * 3;
    const float* pj_ = positions + (long)(b * N + j) * 3;   // gather (L2)

    // dis_vec = pos_j - pos_i + offsets @ cell   (einsum bnmi,bij->bnmj)
    const float dx = pj_[0] - pi_[0] + o0 * c00 + o1 * c10 + o2 * c20;
    const float dy = pj_[1] - pi_[1] + o0 * c01 + o1 * c11 + o2 * c21;
    const float dz = pj_[2] - pi_[2] + o0 * c02 + o1 * c12 + o2 * c22;

    const float d = sqrtf(dx * dx + dy * dy + dz * dz + 1e-12f);

    // cut = mask ? ((d<rc) ? 0.5*(cos(pi*d/rc)+1)/d : 0) : 0
    float cut = 0.0f;
    if (msk != 0.0f && d < 6.0f) {
        cut = 0.5f * (cosf(d * 0.52359877559829887f) + 1.0f) / d;
    }

    cut_s[pr][m] = cut;
    __syncthreads();

    // ---- rare path (~0.45% of lanes): stable descending rank + scatter ----
    // rank(m) = #{k: cut_k > cut_m} + #{k<m: cut_k == cut_m}
    // == position under stable argsort(-cut). Zero-cut entries sort after all
    // nonzero ones and would write exact zeros -> rows are already zero.
    if (cut != 0.0f) {
        int rank = 0;
        const float4* c4 = (const float4*)cut_s[pr];
        #pragma unroll
        for (int k4 = 0; k4 < M_NB / 4; ++k4) {
            const float4 c = c4[k4];             // ds_read_b128 broadcast
            const int k = 4 * k4;
            rank += (c.x > cut) || (c.x == cut && k + 0 < m);
            rank += (c.y > cut) || (c.y == cut && k + 1 < m);
            rank += (c.z > cut) || (c.z == cut && k + 2 < m);
            rank += (c.w > cut) || (c.w == cut && k + 3 < m);
        }
        float* dst = out + (size_t)p * OUT_W + rank * 3;
        dst[0] = cut * dx;
        dst[1] = cut * dy;
        dst[2] = cut * dz;
    }
}

extern "C" void kernel_launch(void* const* d_in, const int* in_sizes, int n_in,
                              void* d_out, int out_size, void* d_ws, size_t ws_size,
                              hipStream_t stream) {
    const float* positions = (const float*)d_in[0];
    const float* cell      = (const float*)d_in[1];
    const float* offsets   = (const float*)d_in[2];
    const float* mask      = (const float*)d_in[3];
    const int*   neighbors = (const int*)d_in[4];
    float*       out       = (float*)d_out;

    const int BN = in_sizes[0] / 3;        // B*N = 32768
    const int B  = in_sizes[1] / 9;        // 8
    const int N  = BN / B;                 // 4096

    // 1) zero-fill the output (49 MB pure store stream, ~6 TB/s)
    const int total4 = out_size / 4;       // out_size % 4 == 0 (384-wide rows)
    fill_zero_kernel<<<2048, 256, 0, stream>>>((float4*)out, total4);

    // 2) store-free compute + rare scatter (stream order: after fill)
    dim3 block(M_NB, PPB, 1);              // 96 x 2 = 192 threads
    dim3 grid(BN / PPB, 1, 1);             // 16384 blocks
    deepmd_angular_compute<<<grid, block, 0, stream>>>(
        positions, cell, offsets, mask, neighbors, out, N);
}